// Round 15
// baseline (171.842 us; speedup 1.0000x reference)
//
#include <hip/hip_runtime.h>

#define R   256
#define S   128
#define CM  256
#define CH  32
#define CZ  128

typedef __attribute__((ext_vector_type(8))) short short8;
typedef __attribute__((ext_vector_type(4))) float f32x4;
typedef unsigned short ushort_t;

__device__ inline ushort_t f2bf(float f) {
    union { float f; unsigned u; } v; v.f = f;
    unsigned u = v.u;
    unsigned r = u + 0x7FFF + ((u >> 16) & 1);
    return (ushort_t)(r >> 16);
}

// ---------------------------------------------------------------------------
// K1 (merged): LN+proj (blocks [0,512)), scale (blocks [512,1536)),
// WTp transpose (blocks [1536,1664)). R12/R14 exact (reproduced twice:
// 149.97 / 148.83 us). DO NOT MODIFY.
// ---------------------------------------------------------------------------
__global__ __launch_bounds__(256) void k_lnproj(
    const float* __restrict__ m, const float* __restrict__ mask,
    const float* __restrict__ g, const float* __restrict__ beta,
    const float* __restrict__ b1, const float* __restrict__ b2,
    const float* __restrict__ w1, const float* __restrict__ w2,
    const float* __restrict__ w_out,
    ushort_t* __restrict__ Abig, ushort_t* __restrict__ BbigT,
    float* __restrict__ scale, ushort_t* __restrict__ WTp) {
    __shared__ ushort_t mnL[64 * CM];      // 32 KB (aliased by scale branch)
    int t = threadIdx.x;
    int b = blockIdx.x;

    if (b >= 1536) {                       // ---- WTp transpose ----
        int z = b - 1536;
        #pragma unroll
        for (int q = 0; q < 4; ++q) {
            int k2 = q * 256 + t;
            int e = k2 >> 5, c = k2 & 31;
            WTp[(size_t)z * 1024 + k2] = f2bf(w_out[(size_t)(c * 32 + e) * CZ + z]);
        }
        return;
    }
    if (b >= 512) {                        // ---- scale ----
        float* red = (float*)mnL;          // [4][64]
        int bb = b - 512;
        int i = bb >> 2, jq = bb & 3;
        int jl = t & 63, wv = t >> 6;
        int j = jq * 64 + jl;
        const float* mi = mask + (size_t)(wv * 32) * R + i;
        const float* mj = mask + (size_t)(wv * 32) * R + j;
        float acc = 0.f;
        #pragma unroll
        for (int s = 0; s < 32; ++s) acc += mi[s * R] * mj[s * R];
        red[wv * 64 + jl] = acc;
        __syncthreads();
        if (t < 64) {
            float v = red[t] + red[64 + t] + red[128 + t] + red[192 + t];
            scale[(size_t)i * R + jq * 64 + t] = 1.0f / (1e-3f + v);
        }
        return;
    }

    // ---- LN + projections ----
    int sg = b & 7, rg = b >> 3;
    int s0 = sg * 16, r0 = rg * 4;
    int w = t >> 6, lane = t & 63, quad = lane >> 4, l15 = lane & 15;

    // Coalesced batch load: wave w owns rows ml = w*16 .. w*16+15.
    // Per row, lane holds floats lane*4..lane*4+3 -> one 1KB load/row/wave.
    float4 xr[16];
    #pragma unroll
    for (int i = 0; i < 16; ++i) {
        int ml = w * 16 + i;
        int r_l = ml >> 4, s_l = ml & 15;
        size_t p = (size_t)(s0 + s_l) * R + (r0 + r_l);
        xr[i] = *(const float4*)(m + p * CM + lane * 4);
    }
    float4 gv = *(const float4*)(g + lane * 4);
    float4 bv = *(const float4*)(beta + lane * 4);

    #pragma unroll
    for (int i = 0; i < 16; ++i) {
        int ml = w * 16 + i;
        float4 a = xr[i];
        float s1 = a.x + a.y + a.z + a.w;
        float s2 = a.x * a.x + a.y * a.y + a.z * a.z + a.w * a.w;
        #pragma unroll
        for (int d = 1; d < 64; d <<= 1) {
            s1 += __shfl_xor(s1, d);
            s2 += __shfl_xor(s2, d);
        }
        float mean = s1 * (1.0f / CM);
        float var  = s2 * (1.0f / CM) - mean * mean;
        float inv  = rsqrtf(var + 1e-5f);
        union { ushort_t u[4]; uint2 v; } pk;
        pk.u[0] = f2bf((a.x - mean) * inv * gv.x + bv.x);
        pk.u[1] = f2bf((a.y - mean) * inv * gv.y + bv.y);
        pk.u[2] = f2bf((a.z - mean) * inv * gv.z + bv.z);
        pk.u[3] = f2bf((a.w - mean) * inv * gv.w + bv.w);
        // lane covers logical chunk ck = lane>>1, half (lane&1); same swizzle
        int ck = lane >> 1;
        int phys = ck ^ (ml & 15);
        *(uint2*)&mnL[ml * CM + phys * 8 + (lane & 1) * 4] = pk.v;
    }

    // W fragments: direct gather from w1/w2 (column ch, stride CH floats).
    int ch = w * 16 + l15;
    const float* wsrc = (ch < CH) ? w1 : w2;
    int cidx = ch & 31;
    short8 bfrs[8];
    #pragma unroll
    for (int ks = 0; ks < 8; ++ks) {
        int cb = ks * 4 + quad;
        union { ushort_t u[8]; short8 v; } pw;
        #pragma unroll
        for (int e = 0; e < 8; ++e)
            pw.u[e] = f2bf(wsrc[(size_t)(cb * 8 + e) * CH + cidx]);
        bfrs[ks] = pw.v;
    }
    __syncthreads();

    f32x4 acc[4];
    #pragma unroll
    for (int a = 0; a < 4; a++) acc[a] = (f32x4)(0.f);
    #pragma unroll
    for (int ks = 0; ks < 8; ++ks) {
        int cb = ks * 4 + quad;
        #pragma unroll
        for (int mt = 0; mt < 4; ++mt) {
            int mm = mt * 16 + l15;
            short8 afr = *(const short8*)&mnL[mm * CM + ((cb ^ l15) << 3)];
            acc[mt] = __builtin_amdgcn_mfma_f32_16x16x32_bf16(afr, bfrs[ks], acc[mt], 0, 0, 0);
        }
    }

    float bias = (ch < CH) ? b1[cidx] : b2[cidx];
    ushort_t* dst = (ch < CH) ? Abig : BbigT;
    #pragma unroll
    for (int mt = 0; mt < 4; ++mt) {
        int r = r0 + mt;
        union { ushort_t u[4]; uint2 v; } pk;
        #pragma unroll
        for (int reg = 0; reg < 4; ++reg) {
            int s = s0 + quad * 4 + reg;
            float mv = mask[(size_t)s * R + r];
            pk.u[reg] = f2bf((acc[mt][reg] + bias) * mv);
        }
        *(uint2*)&dst[((size_t)r * CH + cidx) * S + s0 + quad * 4] = pk.v;
    }
}

// ---------------------------------------------------------------------------
// K2: FUSED outer-product + projection. The per-iteration body is the frozen
// R0 structure, byte-identical (8 failed variants; DO NOT MODIFY the body).
// NEW this round (seam-only wrap): 2 j-tiles per block (512 blocks,
// jb = (b&15)*2 + tile). Amortizes ramp, af/Wp setup, and hides tile-1's
// first B prefetch under tile-0's epilogue stores. Seam hazards audited:
// tile1's shB[0] write is >=2 barriers after its last read; tile1's oc pack
// is after the barrier that closes tile0's stage-2 oc reads.
// Residency 4 -> 2 blocks/CU: benign per R8 (2 blk/CU measured 55.0 us).
// ---------------------------------------------------------------------------
__global__ __launch_bounds__(512, 4) void k_fuse(
    const ushort_t* __restrict__ Abig, const ushort_t* __restrict__ BbigT,
    const ushort_t* __restrict__ WTp, const float* __restrict__ b_out,
    const float* __restrict__ scale, float* __restrict__ out) {
    __shared__ ushort_t oc[64 * 128];        // 16 KB
    __shared__ ushort_t shB[2][32 * 128];    // 2 x 8 KB, [el*8+j][s] swizzled
    int t = threadIdx.x;
    int w = t >> 6, lane = t & 63, quad = lane >> 4, l15 = lane & 15;
    int ib = blockIdx.x >> 4, jb0 = (blockIdx.x & 15) << 1;
    int i_g = ib * 8 + w;
    int jj = l15 & 7, elb = l15 >> 3;

    // A-frags for this wave's i-strip (invariant across both j-tiles)
    short8 af[2][4];
    #pragma unroll
    for (int mt = 0; mt < 2; ++mt)
        #pragma unroll
        for (int ks = 0; ks < 4; ++ks)
            af[mt][ks] = *(const short8*)
                &Abig[((size_t)i_g * 32 + mt * 16 + l15) * S + ks * 32 + quad * 8];

    // B staging: thread t owns LDS row r2 = t>>4 (0..31), 16B chunk ck = t&15
    // global row = jb*256 + (r2&7)*32 + ec*4 + (r2>>3)
    int r2 = t >> 4, ck = t & 15;
    const ushort_t* gB = BbigT
        + ((size_t)jb0 * 256 + (r2 & 7) * 32 + (r2 >> 3)) * S + ck * 8;
    ushort_t* bdst[2];
    bdst[0] = &shB[0][r2 * 128 + ((ck ^ (r2 & 15)) << 3)];
    bdst[1] = &shB[1][r2 * 128 + ((ck ^ (r2 & 15)) << 3)];
    uint4 breg = *(const uint4*)&gB[0];      // prefetch tile0 ec=0

    const ushort_t* Wp = WTp + (size_t)(w * 16 + l15) * 1024 + quad * 8;
    int pwr = w * 8 + jj;                    // oc pair-row this lane writes
    float bz = b_out[w * 16 + l15];

    for (int tile = 0; tile < 2; ++tile) {
        int jb = jb0 + tile;

        f32x4 acc2[4];
        #pragma unroll
        for (int pt = 0; pt < 4; ++pt) acc2[pt] = (f32x4)(0.f);

        for (int ec = 0; ec < 8; ++ec) {
            int buf = ec & 1;
            *(uint4*)bdst[buf] = breg;
            if (ec < 7) breg = *(const uint4*)&gB[(ec + 1) * 512];
            __syncthreads();   // publishes shB[buf]; closes prev stage-2 oc reads

            // ---- stage-1: OC chunk (e = ec*4 .. ec*4+3) ----
            f32x4 acc1[2][2];
            #pragma unroll
            for (int a = 0; a < 2; a++)
                #pragma unroll
                for (int b = 0; b < 2; b++) acc1[a][b] = (f32x4)(0.f);
            #pragma unroll
            for (int ks = 0; ks < 4; ++ks) {
                int chq = ks * 4 + quad;
                int r20 = elb * 8 + jj;          // nt=0: e = ec*4 + elb
                int r21 = r20 + 16;              // nt=1: e = ec*4 + 2 + elb
                short8 bf0 = *(const short8*)
                    &shB[buf][r20 * 128 + ((chq ^ (r20 & 15)) << 3)];
                short8 bf1 = *(const short8*)
                    &shB[buf][r21 * 128 + ((chq ^ (r21 & 15)) << 3)];
                #pragma unroll
                for (int mt = 0; mt < 2; ++mt) {
                    acc1[mt][0] = __builtin_amdgcn_mfma_f32_16x16x32_bf16(
                        af[mt][ks], bf0, acc1[mt][0], 0, 0, 0);
                    acc1[mt][1] = __builtin_amdgcn_mfma_f32_16x16x32_bf16(
                        af[mt][ks], bf1, acc1[mt][1], 0, 0, 0);
                }
            }
            // pack to oc: lane's 4 regs = 4 consecutive c at (pair pwr, e)
            #pragma unroll
            for (int mt = 0; mt < 2; ++mt) {
                int c00 = mt * 16 + quad * 4;
                #pragma unroll
                for (int nt = 0; nt < 2; ++nt) {
                    int el = nt * 2 + elb;
                    int k2l = el * 32 + c00;
                    int cc = k2l >> 3;
                    union { ushort_t u[4]; uint2 v; } pk;
                    #pragma unroll
                    for (int reg = 0; reg < 4; ++reg)
                        pk.u[reg] = f2bf(acc1[mt][nt][reg]);
                    *(uint2*)((char*)oc + pwr * 256 + ((cc ^ (pwr & 7)) << 4)
                              + ((k2l & 7) << 1)) = pk.v;
                }
            }
            __syncthreads();   // publishes oc
            // ---- stage-2: out += OC_chunk x WTp_chunk (wave owns 16 z) ----
            #pragma unroll
            for (int ksl = 0; ksl < 4; ++ksl) {
                short8 wf = *(const short8*)&Wp[ec * 128 + ksl * 32];
                #pragma unroll
                for (int pt = 0; pt < 4; ++pt) {
                    int pp = pt * 16 + l15;
                    int cc = ksl * 4 + quad;
                    short8 of = *(const short8*)
                        ((const char*)oc + pp * 256 + ((cc ^ (pp & 7)) << 4));
                    acc2[pt] = __builtin_amdgcn_mfma_f32_16x16x32_bf16(
                        of, wf, acc2[pt], 0, 0, 0);
                }
            }
        }

        // prefetch next tile's first B slice before the epilogue stores,
        // so its L2 latency hides under them
        if (tile == 0) {
            gB += (size_t)256 * S;               // jb -> jb+1
            breg = *(const uint4*)&gB[0];
        }

        // ---- epilogue: bias + 1/(eps+norm) scale for this tile ----
        #pragma unroll
        for (int pt = 0; pt < 4; ++pt) {
            #pragma unroll
            for (int reg = 0; reg < 4; ++reg) {
                int pp = pt * 16 + quad * 4 + reg;
                int pg = (ib * 8 + (pp >> 3)) * R + jb * 8 + (pp & 7);
                out[(size_t)pg * CZ + w * 16 + l15] = (acc2[pt][reg] + bz) * scale[pg];
            }
        }
    }
}

// ---------------------------------------------------------------------------
extern "C" void kernel_launch(void* const* d_in, const int* in_sizes, int n_in,
                              void* d_out, int out_size, void* d_ws, size_t ws_size,
                              hipStream_t stream) {
    const float* m    = (const float*)d_in[0];
    const float* mask = (const float*)d_in[1];
    const float* g    = (const float*)d_in[2];
    const float* be   = (const float*)d_in[3];
    const float* w1   = (const float*)d_in[4];
    const float* b1   = (const float*)d_in[5];
    const float* w2   = (const float*)d_in[6];
    const float* b2   = (const float*)d_in[7];
    const float* wo   = (const float*)d_in[8];
    const float* bo   = (const float*)d_in[9];
    float* out = (float*)d_out;

    char* ws = (char*)d_ws;
    ushort_t* Abig  = (ushort_t*)ws;                        // 2 MB
    ushort_t* BbigT = Abig + (size_t)R * CH * S;            // 2 MB
    ushort_t* WTp   = BbigT + (size_t)R * CH * S;           // 256 KB
    float*    scale = (float*)(WTp + (size_t)CZ * CH * CH); // 256 KB

    k_lnproj<<<1664, 256, 0, stream>>>(m, mask, g, be, b1, b2, w1, w2, wo,
                                       Abig, BbigT, scale, WTp);
    k_fuse<<<512, 512, 0, stream>>>(Abig, BbigT, WTp, bo, scale, out);
}

// Round 16
// 147.052 us; speedup vs baseline: 1.1686x; 1.1686x over previous
//
#include <hip/hip_runtime.h>

#define R   256
#define S   128
#define CM  256
#define CH  32
#define CZ  128

typedef __attribute__((ext_vector_type(8))) short short8;
typedef __attribute__((ext_vector_type(4))) float f32x4;
typedef unsigned short ushort_t;

__device__ inline ushort_t f2bf(float f) {
    union { float f; unsigned u; } v; v.f = f;
    unsigned u = v.u;
    unsigned r = u + 0x7FFF + ((u >> 16) & 1);
    return (ushort_t)(r >> 16);
}

// ---------------------------------------------------------------------------
// K1 (merged): LN+proj (blocks [0,512)), scale (blocks [512,1536)),
// WTp transpose (blocks [1536,1664)). R12/R14 exact (reproduced twice:
// 149.97 / 148.83 us). FINAL — DO NOT MODIFY.
// ---------------------------------------------------------------------------
__global__ __launch_bounds__(256) void k_lnproj(
    const float* __restrict__ m, const float* __restrict__ mask,
    const float* __restrict__ g, const float* __restrict__ beta,
    const float* __restrict__ b1, const float* __restrict__ b2,
    const float* __restrict__ w1, const float* __restrict__ w2,
    const float* __restrict__ w_out,
    ushort_t* __restrict__ Abig, ushort_t* __restrict__ BbigT,
    float* __restrict__ scale, ushort_t* __restrict__ WTp) {
    __shared__ ushort_t mnL[64 * CM];      // 32 KB (aliased by scale branch)
    int t = threadIdx.x;
    int b = blockIdx.x;

    if (b >= 1536) {                       // ---- WTp transpose ----
        int z = b - 1536;
        #pragma unroll
        for (int q = 0; q < 4; ++q) {
            int k2 = q * 256 + t;
            int e = k2 >> 5, c = k2 & 31;
            WTp[(size_t)z * 1024 + k2] = f2bf(w_out[(size_t)(c * 32 + e) * CZ + z]);
        }
        return;
    }
    if (b >= 512) {                        // ---- scale ----
        float* red = (float*)mnL;          // [4][64]
        int bb = b - 512;
        int i = bb >> 2, jq = bb & 3;
        int jl = t & 63, wv = t >> 6;
        int j = jq * 64 + jl;
        const float* mi = mask + (size_t)(wv * 32) * R + i;
        const float* mj = mask + (size_t)(wv * 32) * R + j;
        float acc = 0.f;
        #pragma unroll
        for (int s = 0; s < 32; ++s) acc += mi[s * R] * mj[s * R];
        red[wv * 64 + jl] = acc;
        __syncthreads();
        if (t < 64) {
            float v = red[t] + red[64 + t] + red[128 + t] + red[192 + t];
            scale[(size_t)i * R + jq * 64 + t] = 1.0f / (1e-3f + v);
        }
        return;
    }

    // ---- LN + projections ----
    int sg = b & 7, rg = b >> 3;
    int s0 = sg * 16, r0 = rg * 4;
    int w = t >> 6, lane = t & 63, quad = lane >> 4, l15 = lane & 15;

    // Coalesced batch load: wave w owns rows ml = w*16 .. w*16+15.
    // Per row, lane holds floats lane*4..lane*4+3 -> one 1KB load/row/wave.
    float4 xr[16];
    #pragma unroll
    for (int i = 0; i < 16; ++i) {
        int ml = w * 16 + i;
        int r_l = ml >> 4, s_l = ml & 15;
        size_t p = (size_t)(s0 + s_l) * R + (r0 + r_l);
        xr[i] = *(const float4*)(m + p * CM + lane * 4);
    }
    float4 gv = *(const float4*)(g + lane * 4);
    float4 bv = *(const float4*)(beta + lane * 4);

    #pragma unroll
    for (int i = 0; i < 16; ++i) {
        int ml = w * 16 + i;
        float4 a = xr[i];
        float s1 = a.x + a.y + a.z + a.w;
        float s2 = a.x * a.x + a.y * a.y + a.z * a.z + a.w * a.w;
        #pragma unroll
        for (int d = 1; d < 64; d <<= 1) {
            s1 += __shfl_xor(s1, d);
            s2 += __shfl_xor(s2, d);
        }
        float mean = s1 * (1.0f / CM);
        float var  = s2 * (1.0f / CM) - mean * mean;
        float inv  = rsqrtf(var + 1e-5f);
        union { ushort_t u[4]; uint2 v; } pk;
        pk.u[0] = f2bf((a.x - mean) * inv * gv.x + bv.x);
        pk.u[1] = f2bf((a.y - mean) * inv * gv.y + bv.y);
        pk.u[2] = f2bf((a.z - mean) * inv * gv.z + bv.z);
        pk.u[3] = f2bf((a.w - mean) * inv * gv.w + bv.w);
        // lane covers logical chunk ck = lane>>1, half (lane&1); same swizzle
        int ck = lane >> 1;
        int phys = ck ^ (ml & 15);
        *(uint2*)&mnL[ml * CM + phys * 8 + (lane & 1) * 4] = pk.v;
    }

    // W fragments: direct gather from w1/w2 (column ch, stride CH floats).
    int ch = w * 16 + l15;
    const float* wsrc = (ch < CH) ? w1 : w2;
    int cidx = ch & 31;
    short8 bfrs[8];
    #pragma unroll
    for (int ks = 0; ks < 8; ++ks) {
        int cb = ks * 4 + quad;
        union { ushort_t u[8]; short8 v; } pw;
        #pragma unroll
        for (int e = 0; e < 8; ++e)
            pw.u[e] = f2bf(wsrc[(size_t)(cb * 8 + e) * CH + cidx]);
        bfrs[ks] = pw.v;
    }
    __syncthreads();

    f32x4 acc[4];
    #pragma unroll
    for (int a = 0; a < 4; a++) acc[a] = (f32x4)(0.f);
    #pragma unroll
    for (int ks = 0; ks < 8; ++ks) {
        int cb = ks * 4 + quad;
        #pragma unroll
        for (int mt = 0; mt < 4; ++mt) {
            int mm = mt * 16 + l15;
            short8 afr = *(const short8*)&mnL[mm * CM + ((cb ^ l15) << 3)];
            acc[mt] = __builtin_amdgcn_mfma_f32_16x16x32_bf16(afr, bfrs[ks], acc[mt], 0, 0, 0);
        }
    }

    float bias = (ch < CH) ? b1[cidx] : b2[cidx];
    ushort_t* dst = (ch < CH) ? Abig : BbigT;
    #pragma unroll
    for (int mt = 0; mt < 4; ++mt) {
        int r = r0 + mt;
        union { ushort_t u[4]; uint2 v; } pk;
        #pragma unroll
        for (int reg = 0; reg < 4; ++reg) {
            int s = s0 + quad * 4 + reg;
            float mv = mask[(size_t)s * R + r];
            pk.u[reg] = f2bf((acc[mt][reg] + bias) * mv);
        }
        *(uint2*)&dst[((size_t)r * CH + cidx) * S + s0 + quad * 4] = pk.v;
    }
}

// ---------------------------------------------------------------------------
// K2: FUSED outer-product + projection — EXACT R0 structure, 1024 blocks,
// one j-tile per block. FINAL — frozen after 9 structural variants all
// regressed or were neutral (prefetch hoist, no-LDS-B, 1-barrier+wreg,
// 4-bit-swz+1:2W, 2-phase, 1:2W-in-stream, 32x32 stage-2, scale prologue,
// j-tile batching — the last two broke the compiler's unroll/regalloc and
// caused scratch-spill traffic). Counters at this point: MfmaUtil ~24%,
// LDS-datapath ~56% busy, HBM ~10%, conflicts 5.24M — dependency-bound
// local minimum, no saturated pipe.
// ---------------------------------------------------------------------------
__global__ __launch_bounds__(512, 4) void k_fuse(
    const ushort_t* __restrict__ Abig, const ushort_t* __restrict__ BbigT,
    const ushort_t* __restrict__ WTp, const float* __restrict__ b_out,
    const float* __restrict__ scale, float* __restrict__ out) {
    __shared__ ushort_t oc[64 * 128];        // 16 KB
    __shared__ ushort_t shB[2][32 * 128];    // 2 x 8 KB, [el*8+j][s] swizzled
    int t = threadIdx.x;
    int w = t >> 6, lane = t & 63, quad = lane >> 4, l15 = lane & 15;
    int ib = blockIdx.x >> 5, jb = blockIdx.x & 31;
    int i_g = ib * 8 + w;
    int jj = l15 & 7, elb = l15 >> 3;

    // A-frags for this wave's i-strip (register-resident, coalesced loads)
    short8 af[2][4];
    #pragma unroll
    for (int mt = 0; mt < 2; ++mt)
        #pragma unroll
        for (int ks = 0; ks < 4; ++ks)
            af[mt][ks] = *(const short8*)
                &Abig[((size_t)i_g * 32 + mt * 16 + l15) * S + ks * 32 + quad * 8];

    // B staging: thread t owns LDS row r2 = t>>4 (0..31), 16B chunk ck = t&15
    // global row = jb*256 + (r2&7)*32 + ec*4 + (r2>>3)
    int r2 = t >> 4, ck = t & 15;
    const ushort_t* gB = BbigT
        + ((size_t)jb * 256 + (r2 & 7) * 32 + (r2 >> 3)) * S + ck * 8;
    ushort_t* bdst[2];
    bdst[0] = &shB[0][r2 * 128 + ((ck ^ (r2 & 15)) << 3)];
    bdst[1] = &shB[1][r2 * 128 + ((ck ^ (r2 & 15)) << 3)];
    uint4 breg = *(const uint4*)&gB[0];      // prefetch ec=0 (e += 4 <=> +512)

    const ushort_t* Wp = WTp + (size_t)(w * 16 + l15) * 1024 + quad * 8;
    int pwr = w * 8 + jj;                    // oc pair-row this lane writes

    f32x4 acc2[4];
    #pragma unroll
    for (int pt = 0; pt < 4; ++pt) acc2[pt] = (f32x4)(0.f);

    for (int ec = 0; ec < 8; ++ec) {
        int buf = ec & 1;
        *(uint4*)bdst[buf] = breg;
        if (ec < 7) breg = *(const uint4*)&gB[(ec + 1) * 512];
        __syncthreads();   // publishes shB[buf]; closes prev stage-2 oc reads

        // ---- stage-1: OC chunk (e = ec*4 .. ec*4+3) ----
        f32x4 acc1[2][2];
        #pragma unroll
        for (int a = 0; a < 2; a++)
            #pragma unroll
            for (int b = 0; b < 2; b++) acc1[a][b] = (f32x4)(0.f);
        #pragma unroll
        for (int ks = 0; ks < 4; ++ks) {
            int chq = ks * 4 + quad;
            int r20 = elb * 8 + jj;          // nt=0: e = ec*4 + elb
            int r21 = r20 + 16;              // nt=1: e = ec*4 + 2 + elb
            short8 bf0 = *(const short8*)
                &shB[buf][r20 * 128 + ((chq ^ (r20 & 15)) << 3)];
            short8 bf1 = *(const short8*)
                &shB[buf][r21 * 128 + ((chq ^ (r21 & 15)) << 3)];
            #pragma unroll
            for (int mt = 0; mt < 2; ++mt) {
                acc1[mt][0] = __builtin_amdgcn_mfma_f32_16x16x32_bf16(
                    af[mt][ks], bf0, acc1[mt][0], 0, 0, 0);
                acc1[mt][1] = __builtin_amdgcn_mfma_f32_16x16x32_bf16(
                    af[mt][ks], bf1, acc1[mt][1], 0, 0, 0);
            }
        }
        // pack to oc: lane's 4 regs = 4 consecutive c at (pair pwr, e)
        #pragma unroll
        for (int mt = 0; mt < 2; ++mt) {
            int c00 = mt * 16 + quad * 4;
            #pragma unroll
            for (int nt = 0; nt < 2; ++nt) {
                int el = nt * 2 + elb;
                int k2l = el * 32 + c00;
                int cc = k2l >> 3;
                union { ushort_t u[4]; uint2 v; } pk;
                #pragma unroll
                for (int reg = 0; reg < 4; ++reg)
                    pk.u[reg] = f2bf(acc1[mt][nt][reg]);
                *(uint2*)((char*)oc + pwr * 256 + ((cc ^ (pwr & 7)) << 4)
                          + ((k2l & 7) << 1)) = pk.v;
            }
        }
        __syncthreads();   // publishes oc
        // ---- stage-2: out += OC_chunk x WTp_chunk (wave owns 16 z) ----
        #pragma unroll
        for (int ksl = 0; ksl < 4; ++ksl) {
            short8 wf = *(const short8*)&Wp[ec * 128 + ksl * 32];
            #pragma unroll
            for (int pt = 0; pt < 4; ++pt) {
                int pp = pt * 16 + l15;
                int cc = ksl * 4 + quad;
                short8 of = *(const short8*)
                    ((const char*)oc + pp * 256 + ((cc ^ (pp & 7)) << 4));
                acc2[pt] = __builtin_amdgcn_mfma_f32_16x16x32_bf16(
                    of, wf, acc2[pt], 0, 0, 0);
            }
        }
    }

    // ---- epilogue: bias + 1/(eps+norm) scale ----
    float bz = b_out[w * 16 + l15];
    #pragma unroll
    for (int pt = 0; pt < 4; ++pt) {
        #pragma unroll
        for (int reg = 0; reg < 4; ++reg) {
            int pp = pt * 16 + quad * 4 + reg;
            int pg = (ib * 8 + (pp >> 3)) * R + jb * 8 + (pp & 7);
            out[(size_t)pg * CZ + w * 16 + l15] = (acc2[pt][reg] + bz) * scale[pg];
        }
    }
}

// ---------------------------------------------------------------------------
extern "C" void kernel_launch(void* const* d_in, const int* in_sizes, int n_in,
                              void* d_out, int out_size, void* d_ws, size_t ws_size,
                              hipStream_t stream) {
    const float* m    = (const float*)d_in[0];
    const float* mask = (const float*)d_in[1];
    const float* g    = (const float*)d_in[2];
    const float* be   = (const float*)d_in[3];
    const float* w1   = (const float*)d_in[4];
    const float* b1   = (const float*)d_in[5];
    const float* w2   = (const float*)d_in[6];
    const float* b2   = (const float*)d_in[7];
    const float* wo   = (const float*)d_in[8];
    const float* bo   = (const float*)d_in[9];
    float* out = (float*)d_out;

    char* ws = (char*)d_ws;
    ushort_t* Abig  = (ushort_t*)ws;                        // 2 MB
    ushort_t* BbigT = Abig + (size_t)R * CH * S;            // 2 MB
    ushort_t* WTp   = BbigT + (size_t)R * CH * S;           // 256 KB
    float*    scale = (float*)(WTp + (size_t)CZ * CH * CH); // 256 KB

    k_lnproj<<<1664, 256, 0, stream>>>(m, mask, g, be, b1, b2, w1, w2, wo,
                                       Abig, BbigT, scale, WTp);
    k_fuse<<<1024, 512, 0, stream>>>(Abig, BbigT, WTp, bo, scale, out);
}